// Round 1
// baseline (670.647 us; speedup 1.0000x reference)
//
#include <hip/hip_runtime.h>

// BlockDiagonalAggregator: out[b,:] = sum_k softmax_k(<keys[sigma[b,k]], h[b,k,:]>) * h[b,k,:]
// B=4096, K=64, D=512, N_AGENTS=64 (sigma==64 -> unassigned -> logit=-1e9)
//
// One block (512 threads = 8 waves) per batch row b. h[b] (128 KiB) is read
// from HBM exactly ONCE and cached in registers (64 f32/thread): thread
// (wave w, lane l) owns dims [l*8, l*8+8) of k-rows {8w..8w+7}.

constexpr int K  = 64;
constexpr int D  = 512;
constexpr int NA = 64;
#define NEG_INF (-1e9f)

__global__ __launch_bounds__(512)
void bda_kernel(const float* __restrict__ h, const float* __restrict__ keys,
                const int* __restrict__ sigma, float* __restrict__ out) {
    const int b    = blockIdx.x;
    const int tid  = threadIdx.x;
    const int w    = tid >> 6;    // wave 0..7
    const int lane = tid & 63;

    __shared__ float lg[K];                       // logits
    __shared__ __align__(16) float obuf[8 * D];   // per-wave partial outputs

    const float* hb = h + (size_t)b * (K * D);
    float4 h0[8], h1[8];   // register cache of h[b, 8w+kk, lane*8 .. lane*8+8)

    // ---- Phase 1: load h into regs, compute logits --------------------------
#pragma unroll
    for (int kk = 0; kk < 8; ++kk) {
        const int k = (w << 3) + kk;
        const float* hrow = hb + k * D + (lane << 3);
        h0[kk] = ((const float4*)hrow)[0];
        h1[kk] = ((const float4*)hrow)[1];

        const int sg = sigma[b * K + k];   // wave-uniform -> scalar load
        float dacc = NEG_INF;
        if (sg < NA) {                     // wave-uniform branch
            const float* krow = keys + sg * D + (lane << 3);
            const float4 k0 = ((const float4*)krow)[0];
            const float4 k1 = ((const float4*)krow)[1];
            dacc = h0[kk].x * k0.x + h0[kk].y * k0.y
                 + h0[kk].z * k0.z + h0[kk].w * k0.w
                 + h1[kk].x * k1.x + h1[kk].y * k1.y
                 + h1[kk].z * k1.z + h1[kk].w * k1.w;
#pragma unroll
            for (int off = 32; off > 0; off >>= 1)
                dacc += __shfl_xor(dacc, off, 64);
        }
        if (lane == 0) lg[k] = dacc;
    }
    __syncthreads();

    // ---- Softmax stats: butterfly over the 64 logits (each wave redundant) --
    const float v = lg[lane];
    float m = v;
#pragma unroll
    for (int off = 32; off > 0; off >>= 1)
        m = fmaxf(m, __shfl_xor(m, off, 64));
    float s = __expf(v - m);
#pragma unroll
    for (int off = 32; off > 0; off >>= 1)
        s += __shfl_xor(s, off, 64);
    const float inv_s = 1.0f / s;
    // Note: if every slot is unassigned, m = -1e9, exp(0)=1, alpha = 1/64 —
    // identical to the reference's softmax over all-(-1e9) logits.

    // ---- Phase 2: weighted pooling from the register cache ------------------
    float4 a0 = make_float4(0.f, 0.f, 0.f, 0.f);
    float4 a1 = make_float4(0.f, 0.f, 0.f, 0.f);
#pragma unroll
    for (int kk = 0; kk < 8; ++kk) {
        const int k = (w << 3) + kk;
        const float al = __expf(lg[k] - m) * inv_s;  // LDS broadcast read
        a0.x += al * h0[kk].x;  a0.y += al * h0[kk].y;
        a0.z += al * h0[kk].z;  a0.w += al * h0[kk].w;
        a1.x += al * h1[kk].x;  a1.y += al * h1[kk].y;
        a1.z += al * h1[kk].z;  a1.w += al * h1[kk].w;
    }
    float* ob = obuf + w * D + (lane << 3);
    ((float4*)ob)[0] = a0;
    ((float4*)ob)[1] = a1;
    __syncthreads();

    // ---- Cross-wave reduce + coalesced store --------------------------------
    float r = 0.f;
#pragma unroll
    for (int w2 = 0; w2 < 8; ++w2)
        r += obuf[w2 * D + tid];          // stride-1 across lanes: conflict-free
    out[(size_t)b * D + tid] = r;
}

extern "C" void kernel_launch(void* const* d_in, const int* in_sizes, int n_in,
                              void* d_out, int out_size, void* d_ws, size_t ws_size,
                              hipStream_t stream) {
    const float* h     = (const float*)d_in[0];
    const float* keys  = (const float*)d_in[1];
    const int*   sigma = (const int*)d_in[2];
    float*       out   = (float*)d_out;
    const int B = in_sizes[2] / K;   // sigma has B*K elements
    bda_kernel<<<dim3(B), dim3(512), 0, stream>>>(h, keys, sigma, out);
}